// Round 1
// baseline (354.707 us; speedup 1.0000x reference)
//
#include <hip/hip_runtime.h>
#include <math.h>

#define N_NODES 100000
#define N_EDGES 1200000
#define DIM 64
#define ELL_STRIDE 48        // ints per node row; deg<=48 safe (Poisson(12))
#define GEMM_BLOCKS ((N_NODES + 63) / 64)      // 1563 (64 nodes/block)
#define FILL_BLOCKS ((N_EDGES + 255) / 256)    // 4688
#define ELL_INT4 (N_NODES * ELL_STRIDE / 4)    // 1,200,000 int4s
#define CUR_INT4 (N_NODES / 4)                 // 25,000 int4s

// bf16 pack/unpack (RTNE)
__device__ __forceinline__ unsigned short f2bf(float f) {
    union { float f; unsigned int u; } v; v.f = f;
    unsigned int r = v.u + 0x7FFF + ((v.u >> 16) & 1);
    return (unsigned short)(r >> 16);
}
__device__ __forceinline__ float bf2f(unsigned short us) {
    return __uint_as_float((unsigned int)us << 16);
}

// ---------------- init: ELL pre-filled with dummy node; cur zeroed ----------
// Gather reads slots [0, max(16, ceil8(deg))); slots >= deg must point at the
// zero dummy row (N_NODES). Pre-fill everything, fill overwrites [0, deg).

__global__ void k_init(int4* __restrict__ ell4, int4* __restrict__ cur4) {
    int gid = blockIdx.x * 256 + threadIdx.x;
    if (gid < ELL_INT4) {
        ell4[gid] = make_int4(N_NODES, N_NODES, N_NODES, N_NODES);
    } else if (gid < ELL_INT4 + CUR_INT4) {
        cur4[gid - ELL_INT4] = make_int4(0, 0, 0, 0);
    }
}

// ---------------- gemm tile: 64 nodes/block, LDS-staged x, W in VGPRs -------

template <bool SCALE>
__device__ __forceinline__ void gemm_block(int bid, const float* __restrict__ x,
                                           const float* __restrict__ W,
                                           unsigned short* __restrict__ h,
                                           const int* __restrict__ deg) {
    __shared__ float4 Xlds[1024];           // 64 rows x 16 float4 = 16 KB
    const int tid = threadIdx.x;
    const int lane = tid & 63;

    float wreg[64];                         // W column for this lane (L2-hot)
#pragma unroll
    for (int k = 0; k < 64; ++k) wreg[k] = W[k * DIM + lane];

    const int base = bid * 64;
#pragma unroll
    for (int it = 0; it < 4; ++it) {
        int f = tid + it * 256;             // float4 index in tile
        int row = base + (f >> 4);
        if (row >= N_NODES) row = N_NODES - 1;          // clamp (value unused)
        Xlds[f] = ((const float4*)x)[row * 16 + (f & 15)];
    }
    __syncthreads();

    const int m0 = (tid >> 6) * 16;         // wave's 16 rows
    for (int m = 0; m < 16; ++m) {
        const float4* xr = &Xlds[(m0 + m) * 16];
        float a0 = 0.f, a1 = 0.f, a2 = 0.f, a3 = 0.f;
#pragma unroll
        for (int k4 = 0; k4 < 16; ++k4) {
            float4 xv = xr[k4];             // uniform b128 broadcast
            a0 = fmaf(xv.x, wreg[k4 * 4 + 0], a0);
            a1 = fmaf(xv.y, wreg[k4 * 4 + 1], a1);
            a2 = fmaf(xv.z, wreg[k4 * 4 + 2], a2);
            a3 = fmaf(xv.w, wreg[k4 * 4 + 3], a3);
        }
        int row = base + m0 + m;
        if (row < N_NODES) {
            float res = (a0 + a1) + (a2 + a3);
            if (SCALE) res *= rsqrtf((float)(deg[row] + 1));
            h[(size_t)row * DIM + lane] = f2bf(res);
        }
    }
}

__global__ void __launch_bounds__(256, 4) k_gemm(const float* __restrict__ x,
                                                 const float* __restrict__ W,
                                                 unsigned short* __restrict__ h,
                                                 const int* __restrict__ deg) {
    gemm_block<true>(blockIdx.x, x, W, h, deg);
}

// ---------------- fused: gemm1 (blocks 0..1562)  ||  direct ELL scatter -----
// Per-NODE atomics (100k counters, chain depth ~Poisson(12)) instead of the
// old per-bucket tails (782 counters, 1536-deep serial chains). Edge lands
// directly in its ELL row; no part buffer, no k_build.

__global__ void __launch_bounds__(256, 4) k_pre(const int* __restrict__ ei,
                                                const float* __restrict__ x,
                                                const float* __restrict__ W1,
                                                int* __restrict__ cur,
                                                int* __restrict__ ell,
                                                unsigned short* __restrict__ h) {
    if (blockIdx.x < GEMM_BLOCKS) {
        gemm_block<false>(blockIdx.x, x, W1, h, nullptr);
        return;
    }
    int e = (blockIdx.x - GEMM_BLOCKS) * 256 + threadIdx.x;
    if (e < N_EDGES) {
        int s = ei[e], d = ei[N_EDGES + e];
        int pos = atomicAdd(&cur[d], 1);
        if (pos < ELL_STRIDE) ell[(size_t)d * ELL_STRIDE + pos] = s;
    }
}

// ---------------- scale pass: h1 *= dinv[row]; zero dummy row --------------

__device__ __forceinline__ unsigned int scale2(unsigned int u, float dd) {
    float lo = __uint_as_float(u << 16) * dd;
    float hi = __uint_as_float(u & 0xFFFF0000u) * dd;
    return (unsigned int)f2bf(lo) | ((unsigned int)f2bf(hi) << 16);
}

__global__ void k_scale(unsigned short* __restrict__ h, const int* __restrict__ deg) {
    int gid = blockIdx.x * 256 + threadIdx.x;        // uint4 index (8 bf16)
    if (gid >= (N_NODES + 1) * 8) return;
    int row = gid >> 3;
    uint4* p = (uint4*)h + gid;
    if (row == N_NODES) { *p = make_uint4(0, 0, 0, 0); return; }
    float dd = rsqrtf((float)(deg[row] + 1));
    uint4 v = *p;
    v.x = scale2(v.x, dd);
    v.y = scale2(v.y, dd);
    v.z = scale2(v.z, dd);
    v.w = scale2(v.w, dd);
    *p = v;
}

// ---------------- gather: out = relu?( dinv[d]*(sum h'[s] + h'[d]) + b ) ----

template <bool RELU_OUT>
__global__ void k_gather(const unsigned short* __restrict__ h,
                         const int* __restrict__ deg,
                         const int* __restrict__ ell, const float* __restrict__ b,
                         float* __restrict__ out) {
    int node = blockIdx.x * 4 + (threadIdx.x >> 6);     // 25000*4 = 100000 exact
    const int lane = threadIdx.x & 63;
    int dg = __builtin_amdgcn_readfirstlane(deg[node]);
    const int* row = ell + (size_t)node * ELL_STRIDE;

    int4 e0 = ((const int4*)row)[0];
    int4 e1 = ((const int4*)row)[1];
    int4 e2 = ((const int4*)row)[2];
    int4 e3 = ((const int4*)row)[3];
    float own = bf2f(h[(size_t)node * DIM + lane]);     // self-loop (coalesced)

    float v0  = bf2f(h[(size_t)e0.x * DIM + lane]);
    float v1  = bf2f(h[(size_t)e0.y * DIM + lane]);
    float v2  = bf2f(h[(size_t)e0.z * DIM + lane]);
    float v3  = bf2f(h[(size_t)e0.w * DIM + lane]);
    float v4  = bf2f(h[(size_t)e1.x * DIM + lane]);
    float v5  = bf2f(h[(size_t)e1.y * DIM + lane]);
    float v6  = bf2f(h[(size_t)e1.z * DIM + lane]);
    float v7  = bf2f(h[(size_t)e1.w * DIM + lane]);
    float v8  = bf2f(h[(size_t)e2.x * DIM + lane]);
    float v9  = bf2f(h[(size_t)e2.y * DIM + lane]);
    float v10 = bf2f(h[(size_t)e2.z * DIM + lane]);
    float v11 = bf2f(h[(size_t)e2.w * DIM + lane]);
    float v12 = bf2f(h[(size_t)e3.x * DIM + lane]);
    float v13 = bf2f(h[(size_t)e3.y * DIM + lane]);
    float v14 = bf2f(h[(size_t)e3.z * DIM + lane]);
    float v15 = bf2f(h[(size_t)e3.w * DIM + lane]);

    float acc = ((own + v0) + (v1 + v2)) + ((v3 + v4) + (v5 + v6))
              + ((v7 + v8) + (v9 + v10)) + ((v11 + v12) + ((v13 + v14) + v15));

    if (dg > 16) {                                      // rare, wave-uniform
        int pe = (dg + 7) & ~7;
        for (int k = 16; k < pe; k += 8) {
            int4 a = *(const int4*)(row + k);
            int4 c = *(const int4*)(row + k + 4);
            float w0 = bf2f(h[(size_t)a.x * DIM + lane]);
            float w1 = bf2f(h[(size_t)a.y * DIM + lane]);
            float w2 = bf2f(h[(size_t)a.z * DIM + lane]);
            float w3 = bf2f(h[(size_t)a.w * DIM + lane]);
            float w4 = bf2f(h[(size_t)c.x * DIM + lane]);
            float w5 = bf2f(h[(size_t)c.y * DIM + lane]);
            float w6 = bf2f(h[(size_t)c.z * DIM + lane]);
            float w7 = bf2f(h[(size_t)c.w * DIM + lane]);
            acc += ((w0 + w1) + (w2 + w3)) + ((w4 + w5) + (w6 + w7));
        }
    }

    float dd = rsqrtf((float)(dg + 1));
    float o = fmaf(acc, dd, b[lane]);
    if (RELU_OUT) o = fmaxf(o, 0.f);
    out[(size_t)node * DIM + lane] = o;
}

// ---------------- launch ----------------

extern "C" void kernel_launch(void* const* d_in, const int* in_sizes, int n_in,
                              void* d_out, int out_size, void* d_ws, size_t ws_size,
                              hipStream_t stream) {
    const float* x   = (const float*)d_in[0];
    const int*   ei  = (const int*)d_in[1];     // [2, E] row-major
    const float* W1  = (const float*)d_in[2];
    const float* b1  = (const float*)d_in[3];
    const float* W2  = (const float*)d_in[4];
    const float* b2  = (const float*)d_in[5];
    const float* W3  = (const float*)d_in[6];
    const float* b3  = (const float*)d_in[7];
    float* out = (float*)d_out;

    // ws layout (matches previous footprint; part buffer removed)
    char* ws = (char*)d_ws;
    int*            cur   = (int*)ws;                          // 400 KB (per-node fill cursor == deg)
    int*            ell   = (int*)(ws + 0xD00000);             // 19.2 MB (N_NODES*48*4)
    unsigned short* hbuf  = (unsigned short*)(ws + 0x2000000); // 12.8 MB (bf16 + dummy row)
    float*          gbuf  = (float*)(ws + 0x2D00000);          // 25.6 MB (fp32)

    // pre-fill ELL with dummy node + zero cursors (must precede k_pre fill)
    k_init<<<(ELL_INT4 + CUR_INT4 + 255) / 256, 256, 0, stream>>>((int4*)ell, (int4*)cur);

    // gemm1 (x @ W1 -> hbuf, unscaled)  ||  direct ELL scatter of edges
    k_pre<<<GEMM_BLOCKS + FILL_BLOCKS, 256, 0, stream>>>(ei, x, W1, cur, ell, hbuf);
    k_scale<<<((N_NODES + 1) * 8 + 255) / 256, 256, 0, stream>>>(hbuf, cur);

    const int gather_blocks = N_NODES / 4;   // 25000 (1 wave/node)

    // Layer 1 aggregation (fp32 out)
    k_gather<true><<<gather_blocks, 256, 0, stream>>>(hbuf, cur, ell, b1, gbuf);
    // Layer 2 (gemm scales output rows by dinv)
    k_gemm<<<GEMM_BLOCKS, 256, 0, stream>>>(gbuf, W2, hbuf, cur);
    k_gather<true><<<gather_blocks, 256, 0, stream>>>(hbuf, cur, ell, b2, gbuf);
    // Layer 3
    k_gemm<<<GEMM_BLOCKS, 256, 0, stream>>>(gbuf, W3, hbuf, cur);
    k_gather<false><<<gather_blocks, 256, 0, stream>>>(hbuf, cur, ell, b3, out);
}

// Round 2
// 300.768 us; speedup vs baseline: 1.1793x; 1.1793x over previous
//
#include <hip/hip_runtime.h>
#include <math.h>

#define N_NODES 100000
#define N_EDGES 1200000
#define DIM 64
#define ELL_STRIDE 48        // ints per node row; deg<=48 safe (Poisson(12))
#define BNODES 128           // nodes per bucket (dst>>7)
#define NBUCKET ((N_NODES + BNODES - 1) / BNODES)   // 782 buckets
#define BIN_SHIFT 10         // coarse bin = dst>>10 (1024 nodes)
#define NBIN ((N_NODES + 1023) >> 10)               // 98 bins
#define BIN_CAP 16384        // edges per bin region; mean 12245, +37 sigma
#define CAP 64               // staged edges per bin per fill block; mean 23.9
#define BIN_BLOCKS 512
#define EPB ((N_EDGES + BIN_BLOCKS - 1) / BIN_BLOCKS)  // 2344 edges/block
#define GEMM_BLOCKS ((N_NODES + 63) / 64)      // 1563 (64 nodes/block)

// bf16 pack/unpack (RTNE)
__device__ __forceinline__ unsigned short f2bf(float f) {
    union { float f; unsigned int u; } v; v.f = f;
    unsigned int r = v.u + 0x7FFF + ((v.u >> 16) & 1);
    return (unsigned short)(r >> 16);
}
__device__ __forceinline__ float bf2f(unsigned short us) {
    return __uint_as_float((unsigned int)us << 16);
}

// ---------------- init: zero the 98 bin tails ------------------------------

__global__ void k_init(int* __restrict__ tail) {
    if (threadIdx.x < NBIN) tail[threadIdx.x] = 0;
}

// ---------------- gemm tile: 64 nodes/block, LDS-staged x, W in VGPRs -------

template <bool SCALE>
__device__ __forceinline__ void gemm_block(int bid, const float* __restrict__ x,
                                           const float* __restrict__ W,
                                           unsigned short* __restrict__ h,
                                           const int* __restrict__ deg,
                                           float4* __restrict__ Xlds) {
    const int tid = threadIdx.x;
    const int lane = tid & 63;

    float wreg[64];                         // W column for this lane (L2-hot)
#pragma unroll
    for (int k = 0; k < 64; ++k) wreg[k] = W[k * DIM + lane];

    const int base = bid * 64;
#pragma unroll
    for (int it = 0; it < 4; ++it) {
        int f = tid + it * 256;             // float4 index in tile
        int row = base + (f >> 4);
        if (row >= N_NODES) row = N_NODES - 1;          // clamp (value unused)
        Xlds[f] = ((const float4*)x)[row * 16 + (f & 15)];
    }
    __syncthreads();

    const int m0 = (tid >> 6) * 16;         // wave's 16 rows
    for (int m = 0; m < 16; ++m) {
        const float4* xr = &Xlds[(m0 + m) * 16];
        float a0 = 0.f, a1 = 0.f, a2 = 0.f, a3 = 0.f;
#pragma unroll
        for (int k4 = 0; k4 < 16; ++k4) {
            float4 xv = xr[k4];             // uniform b128 broadcast
            a0 = fmaf(xv.x, wreg[k4 * 4 + 0], a0);
            a1 = fmaf(xv.y, wreg[k4 * 4 + 1], a1);
            a2 = fmaf(xv.z, wreg[k4 * 4 + 2], a2);
            a3 = fmaf(xv.w, wreg[k4 * 4 + 3], a3);
        }
        int row = base + m0 + m;
        if (row < N_NODES) {
            float res = (a0 + a1) + (a2 + a3);
            if (SCALE) res *= rsqrtf((float)(deg[row] + 1));
            h[(size_t)row * DIM + lane] = f2bf(res);
        }
    }
}

__global__ void __launch_bounds__(256, 4) k_gemm(const float* __restrict__ x,
                                                 const float* __restrict__ W,
                                                 unsigned short* __restrict__ h,
                                                 const int* __restrict__ deg) {
    __shared__ float4 Xlds[1024];           // 16 KB
    gemm_block<true>(blockIdx.x, x, W, h, deg, Xlds);
}

// ---------------- fused: gemm1 (blocks 0..1562)  ||  LDS-staged binning -----
// Fill blocks stage edges into 98 coarse bins (dst>>10) in LDS, then flush
// each bin as ONE contiguous segment (exact-count atomicAdd on the bin tail).
// Stores land sequentially per bin -> ~1x write amplification (vs 64B/edge
// for the random-scatter variants, which measured 78-84 MB WRITE_SIZE).

__global__ void __launch_bounds__(256) k_pre(const int* __restrict__ ei,
                                             const float* __restrict__ x,
                                             const float* __restrict__ W1,
                                             int* __restrict__ tail,
                                             int2* __restrict__ part,
                                             unsigned short* __restrict__ h) {
    __shared__ __align__(16) char smraw[NBIN * CAP * 8];   // 50176 B union
    __shared__ int lcnt[NBIN];
    __shared__ int gbase[NBIN];
    __shared__ int gcnt[NBIN];

    if (blockIdx.x < GEMM_BLOCKS) {
        gemm_block<false>(blockIdx.x, x, W1, h, nullptr, (float4*)smraw);
        return;
    }
    int2* stg = (int2*)smraw;
    const int tid = threadIdx.x;
    for (int i = tid; i < NBIN; i += 256) lcnt[i] = 0;
    __syncthreads();

    const int e0 = (blockIdx.x - GEMM_BLOCKS) * EPB;
    const int eend = (e0 + EPB < N_EDGES) ? e0 + EPB : N_EDGES;
    for (int e = e0 + tid; e < eend; e += 256) {
        int s = ei[e], d = ei[N_EDGES + e];
        int bin = d >> BIN_SHIFT;
        int pos = atomicAdd(&lcnt[bin], 1);
        if (pos < CAP) {
            stg[bin * CAP + pos] = make_int2(s, d);
        } else {                              // statistically ~never (>8 sigma)
            int gp = atomicAdd(&tail[bin], 1);
            part[(size_t)bin * BIN_CAP + gp] = make_int2(s, d);
        }
    }
    __syncthreads();
    if (tid < NBIN) {
        int c = lcnt[tid]; if (c > CAP) c = CAP;
        gcnt[tid] = c;
        gbase[tid] = c ? atomicAdd(&tail[tid], c) : 0;
    }
    __syncthreads();
    for (int b = 0; b < NBIN; ++b) {
        int c = gcnt[b];
        int gb = gbase[b];
        for (int i = tid; i < c; i += 256)
            part[(size_t)b * BIN_CAP + gb + i] = stg[b * CAP + i];
    }
}

// ---------------- bucket build: per-bucket ELL slab in LDS, streamed out ----
// One block per 128-node bucket; reads its parent bin's contiguous edge
// segment (L2/L3-hot, 1/8 filter hit), LDS-atomic scatter, coalesced stream.

__global__ void __launch_bounds__(256) k_bucket(const int2* __restrict__ part,
                                                const int* __restrict__ tail,
                                                int* __restrict__ ell,
                                                int* __restrict__ deg) {
    __shared__ int lcur[BNODES];
    __shared__ int lell[BNODES * ELL_STRIDE];   // 24 KB
    const int bucket = blockIdx.x;
    const int tid = threadIdx.x;

    for (int i = tid; i < BNODES; i += 256) lcur[i] = 0;
    __syncthreads();

    const int bin = bucket >> 3;                // dst>>10 == (dst>>7)>>3
    const int n = tail[bin];
    const int2* pb = part + (size_t)bin * BIN_CAP;
    const int node0 = bucket * BNODES;
    for (int i = tid; i < n; i += 256) {
        int2 e = pb[i];
        unsigned ld = (unsigned)(e.y - node0);
        if (ld < BNODES) {
            int pos = atomicAdd(&lcur[ld], 1);
            if (pos < ELL_STRIDE) lell[ld * ELL_STRIDE + pos] = e.x;
        }
    }
    __syncthreads();

    for (int idx = tid; idx < BNODES * ELL_STRIDE; idx += 256) {
        int ln = idx / ELL_STRIDE, sl = idx - ln * ELL_STRIDE;
        int dg = lcur[ln];
        int pe = (dg + 7) & ~7;
        if (pe < 16) pe = 16;
        if (sl >= dg && sl < pe) lell[idx] = N_NODES;   // dummy zero row
    }
    __syncthreads();

    int4* dst4 = (int4*)(ell + (size_t)bucket * BNODES * ELL_STRIDE);
    const int4* src4 = (const int4*)lell;
    for (int i = tid; i < BNODES * ELL_STRIDE / 4; i += 256) dst4[i] = src4[i];
    for (int i = tid; i < BNODES; i += 256) deg[node0 + i] = lcur[i];
}

// ---------------- scale pass: h1 *= dinv[row]; zero dummy row --------------

__device__ __forceinline__ unsigned int scale2(unsigned int u, float dd) {
    float lo = __uint_as_float(u << 16) * dd;
    float hi = __uint_as_float(u & 0xFFFF0000u) * dd;
    return (unsigned int)f2bf(lo) | ((unsigned int)f2bf(hi) << 16);
}

__global__ void k_scale(unsigned short* __restrict__ h, const int* __restrict__ deg) {
    int gid = blockIdx.x * 256 + threadIdx.x;        // uint4 index (8 bf16)
    if (gid >= (N_NODES + 1) * 8) return;
    int row = gid >> 3;
    uint4* p = (uint4*)h + gid;
    if (row == N_NODES) { *p = make_uint4(0, 0, 0, 0); return; }
    float dd = rsqrtf((float)(deg[row] + 1));
    uint4 v = *p;
    v.x = scale2(v.x, dd);
    v.y = scale2(v.y, dd);
    v.z = scale2(v.z, dd);
    v.w = scale2(v.w, dd);
    *p = v;
}

// ---------------- gather: out = relu?( dinv[d]*(sum h'[s] + h'[d]) + b ) ----

template <bool RELU_OUT>
__global__ void k_gather(const unsigned short* __restrict__ h,
                         const int* __restrict__ deg,
                         const int* __restrict__ ell, const float* __restrict__ b,
                         float* __restrict__ out) {
    int node = blockIdx.x * 4 + (threadIdx.x >> 6);     // 25000*4 = 100000 exact
    const int lane = threadIdx.x & 63;
    int dg = __builtin_amdgcn_readfirstlane(deg[node]);
    const int* row = ell + (size_t)node * ELL_STRIDE;

    int4 e0 = ((const int4*)row)[0];
    int4 e1 = ((const int4*)row)[1];
    int4 e2 = ((const int4*)row)[2];
    int4 e3 = ((const int4*)row)[3];
    float own = bf2f(h[(size_t)node * DIM + lane]);     // self-loop (coalesced)

    float v0  = bf2f(h[(size_t)e0.x * DIM + lane]);
    float v1  = bf2f(h[(size_t)e0.y * DIM + lane]);
    float v2  = bf2f(h[(size_t)e0.z * DIM + lane]);
    float v3  = bf2f(h[(size_t)e0.w * DIM + lane]);
    float v4  = bf2f(h[(size_t)e1.x * DIM + lane]);
    float v5  = bf2f(h[(size_t)e1.y * DIM + lane]);
    float v6  = bf2f(h[(size_t)e1.z * DIM + lane]);
    float v7  = bf2f(h[(size_t)e1.w * DIM + lane]);
    float v8  = bf2f(h[(size_t)e2.x * DIM + lane]);
    float v9  = bf2f(h[(size_t)e2.y * DIM + lane]);
    float v10 = bf2f(h[(size_t)e2.z * DIM + lane]);
    float v11 = bf2f(h[(size_t)e2.w * DIM + lane]);
    float v12 = bf2f(h[(size_t)e3.x * DIM + lane]);
    float v13 = bf2f(h[(size_t)e3.y * DIM + lane]);
    float v14 = bf2f(h[(size_t)e3.z * DIM + lane]);
    float v15 = bf2f(h[(size_t)e3.w * DIM + lane]);

    float acc = ((own + v0) + (v1 + v2)) + ((v3 + v4) + (v5 + v6))
              + ((v7 + v8) + (v9 + v10)) + ((v11 + v12) + ((v13 + v14) + v15));

    if (dg > 16) {                                      // rare, wave-uniform
        int pe = (dg + 7) & ~7;
        for (int k = 16; k < pe; k += 8) {
            int4 a = *(const int4*)(row + k);
            int4 c = *(const int4*)(row + k + 4);
            float w0 = bf2f(h[(size_t)a.x * DIM + lane]);
            float w1 = bf2f(h[(size_t)a.y * DIM + lane]);
            float w2 = bf2f(h[(size_t)a.z * DIM + lane]);
            float w3 = bf2f(h[(size_t)a.w * DIM + lane]);
            float w4 = bf2f(h[(size_t)c.x * DIM + lane]);
            float w5 = bf2f(h[(size_t)c.y * DIM + lane]);
            float w6 = bf2f(h[(size_t)c.z * DIM + lane]);
            float w7 = bf2f(h[(size_t)c.w * DIM + lane]);
            acc += ((w0 + w1) + (w2 + w3)) + ((w4 + w5) + (w6 + w7));
        }
    }

    float dd = rsqrtf((float)(dg + 1));
    float o = fmaf(acc, dd, b[lane]);
    if (RELU_OUT) o = fmaxf(o, 0.f);
    out[(size_t)node * DIM + lane] = o;
}

// ---------------- launch ----------------

extern "C" void kernel_launch(void* const* d_in, const int* in_sizes, int n_in,
                              void* d_out, int out_size, void* d_ws, size_t ws_size,
                              hipStream_t stream) {
    const float* x   = (const float*)d_in[0];
    const int*   ei  = (const int*)d_in[1];     // [2, E] row-major
    const float* W1  = (const float*)d_in[2];
    const float* b1  = (const float*)d_in[3];
    const float* W2  = (const float*)d_in[4];
    const float* b2  = (const float*)d_in[5];
    const float* W3  = (const float*)d_in[6];
    const float* b3  = (const float*)d_in[7];
    float* out = (float*)d_out;

    // ws layout (256B-aligned); part overlays gbuf (disjoint lifetimes:
    // part dead after k_bucket; gbuf first written by k_gather L1)
    char* ws = (char*)d_ws;
    int*            deg   = (int*)ws;                          // 448 KB reserve (NBUCKET*BNODES ints)
    int*            tailp = (int*)(ws + 0x70000);              // 98 ints
    int*            ell   = (int*)(ws + 0xD00000);             // 19.2 MB (NBUCKET*BNODES*48*4)
    unsigned short* hbuf  = (unsigned short*)(ws + 0x2000000); // 12.8 MB (bf16 + dummy row)
    float*          gbuf  = (float*)(ws + 0x2D00000);          // 25.6 MB (fp32)
    int2*           part  = (int2*)(ws + 0x2D00000);           // 12.85 MB overlay (NBIN*BIN_CAP*8)

    k_init<<<1, 128, 0, stream>>>(tailp);

    // gemm1 (x @ W1 -> hbuf, unscaled)  ||  LDS-binned edge partition
    k_pre<<<GEMM_BLOCKS + BIN_BLOCKS, 256, 0, stream>>>(ei, x, W1, tailp, part, hbuf);
    k_bucket<<<NBUCKET, 256, 0, stream>>>(part, tailp, ell, deg);
    k_scale<<<((N_NODES + 1) * 8 + 255) / 256, 256, 0, stream>>>(hbuf, deg);

    const int gather_blocks = N_NODES / 4;   // 25000 (1 wave/node)

    // Layer 1 aggregation (fp32 out)
    k_gather<true><<<gather_blocks, 256, 0, stream>>>(hbuf, deg, ell, b1, gbuf);
    // Layer 2 (gemm scales output rows by dinv)
    k_gemm<<<GEMM_BLOCKS, 256, 0, stream>>>(gbuf, W2, hbuf, deg);
    k_gather<true><<<gather_blocks, 256, 0, stream>>>(hbuf, deg, ell, b2, gbuf);
    // Layer 3
    k_gemm<<<GEMM_BLOCKS, 256, 0, stream>>>(gbuf, W3, hbuf, deg);
    k_gather<false><<<gather_blocks, 256, 0, stream>>>(hbuf, deg, ell, b3, out);
}

// Round 3
// 282.881 us; speedup vs baseline: 1.2539x; 1.0632x over previous
//
#include <hip/hip_runtime.h>
#include <math.h>

#define N_NODES 100000
#define N_EDGES 1200000
#define DIM 64
#define ELL_STRIDE 48        // ints per node row; deg<=48 safe (Poisson(12))
#define BNODES 128           // nodes per bucket (dst>>7)
#define NBUCKET ((N_NODES + BNODES - 1) / BNODES)   // 782 buckets
#define BIN_SHIFT 10         // coarse bin = dst>>10 (1024 nodes)
#define NBIN ((N_NODES + 1023) >> 10)               // 98 bins
#define BIN_CAP 16384        // edges per bin region; mean 12245, +37 sigma
#define CAP 40               // staged edges per bin per fill block; mean 23.9, 3.3 sigma
#define BIN_BLOCKS 512
#define EPB ((N_EDGES + BIN_BLOCKS - 1) / BIN_BLOCKS)  // 2344 edges/block
#define GEMM_BLOCKS ((N_NODES + 63) / 64)      // 1563 (64 nodes/block)

// bf16 pack/unpack (RTNE)
__device__ __forceinline__ unsigned short f2bf(float f) {
    union { float f; unsigned int u; } v; v.f = f;
    unsigned int r = v.u + 0x7FFF + ((v.u >> 16) & 1);
    return (unsigned short)(r >> 16);
}
__device__ __forceinline__ float bf2f(unsigned short us) {
    return __uint_as_float((unsigned int)us << 16);
}

// ---------------- init: zero the 98 bin tails (1 line apart) ----------------

__global__ void k_init(int* __restrict__ tail) {
    if (threadIdx.x < NBIN) tail[threadIdx.x * 16] = 0;
}

// ---------------- gemm tile: 64 nodes/block, LDS-staged x, W in VGPRs -------

__device__ __forceinline__ void gemm_block(int bid, const float* __restrict__ x,
                                           const float* __restrict__ W,
                                           unsigned short* __restrict__ h,
                                           float4* __restrict__ Xlds) {
    const int tid = threadIdx.x;
    const int lane = tid & 63;

    float wreg[64];                         // W column for this lane (L2-hot)
#pragma unroll
    for (int k = 0; k < 64; ++k) wreg[k] = W[k * DIM + lane];

    const int base = bid * 64;
#pragma unroll
    for (int it = 0; it < 4; ++it) {
        int f = tid + it * 256;             // float4 index in tile
        int row = base + (f >> 4);
        if (row >= N_NODES) row = N_NODES - 1;          // clamp (value unused)
        Xlds[f] = ((const float4*)x)[row * 16 + (f & 15)];
    }
    __syncthreads();

    const int m0 = (tid >> 6) * 16;         // wave's 16 rows
    for (int m = 0; m < 16; ++m) {
        const float4* xr = &Xlds[(m0 + m) * 16];
        float a0 = 0.f, a1 = 0.f, a2 = 0.f, a3 = 0.f;
#pragma unroll
        for (int k4 = 0; k4 < 16; ++k4) {
            float4 xv = xr[k4];             // uniform b128 broadcast
            a0 = fmaf(xv.x, wreg[k4 * 4 + 0], a0);
            a1 = fmaf(xv.y, wreg[k4 * 4 + 1], a1);
            a2 = fmaf(xv.z, wreg[k4 * 4 + 2], a2);
            a3 = fmaf(xv.w, wreg[k4 * 4 + 3], a3);
        }
        int row = base + m0 + m;
        if (row < N_NODES)
            h[(size_t)row * DIM + lane] = f2bf((a0 + a1) + (a2 + a3));
    }
}

// ---------------- fused: gemm1 (blocks 0..1562)  ||  LDS-staged binning -----
// Fill blocks stage edges into 98 coarse bins (dst>>10) in LDS, then flush
// each bin as ONE contiguous segment (exact-count atomicAdd on the bin tail).

__global__ void __launch_bounds__(256) k_pre(const int* __restrict__ ei,
                                             const float* __restrict__ x,
                                             const float* __restrict__ W1,
                                             int* __restrict__ tail,
                                             int2* __restrict__ part,
                                             unsigned short* __restrict__ h) {
    __shared__ __align__(16) char smraw[NBIN * CAP * 8];   // 31360 B union (>= 16KB gemm tile)
    __shared__ int lcnt[NBIN];
    __shared__ int gbase[NBIN];
    __shared__ int gcnt[NBIN];

    if (blockIdx.x < GEMM_BLOCKS) {
        gemm_block(blockIdx.x, x, W1, h, (float4*)smraw);
        return;
    }
    int2* stg = (int2*)smraw;
    const int tid = threadIdx.x;
    for (int i = tid; i < NBIN; i += 256) lcnt[i] = 0;
    __syncthreads();

    const int e0 = (blockIdx.x - GEMM_BLOCKS) * EPB;
    const int eend = (e0 + EPB < N_EDGES) ? e0 + EPB : N_EDGES;
    for (int e = e0 + tid; e < eend; e += 256) {
        int s = ei[e], d = ei[N_EDGES + e];
        int bin = d >> BIN_SHIFT;
        int pos = atomicAdd(&lcnt[bin], 1);
        if (pos < CAP) {
            stg[bin * CAP + pos] = make_int2(s, d);
        } else {                              // ~3.3-sigma tail, few dozen edges
            int gp = atomicAdd(&tail[bin * 16], 1);
            part[(size_t)bin * BIN_CAP + gp] = make_int2(s, d);
        }
    }
    __syncthreads();
    if (tid < NBIN) {
        int c = lcnt[tid]; if (c > CAP) c = CAP;
        gcnt[tid] = c;
        gbase[tid] = c ? atomicAdd(&tail[tid * 16], c) : 0;
    }
    __syncthreads();
    const int wv = tid >> 6, ln = tid & 63;   // wave-parallel flush (4 bins concurrent)
    for (int b = wv; b < NBIN; b += 4) {
        int c = gcnt[b];
        size_t gbb = (size_t)b * BIN_CAP + gbase[b];
        for (int i = ln; i < c; i += 64)
            part[gbb + i] = stg[b * CAP + i];
    }
}

// ---------------- bucket build: ELL slab in LDS + fused h1 scale ------------

__global__ void __launch_bounds__(256) k_bucket(const int2* __restrict__ part,
                                                const int* __restrict__ tail,
                                                int* __restrict__ ell,
                                                int* __restrict__ deg,
                                                unsigned short* __restrict__ hA,
                                                unsigned short* __restrict__ hB) {
    __shared__ int lcur[BNODES];
    __shared__ int lell[BNODES * ELL_STRIDE];   // 24 KB
    const int bucket = blockIdx.x;
    const int tid = threadIdx.x;

    for (int i = tid; i < BNODES; i += 256) lcur[i] = 0;
    __syncthreads();

    const int bin = bucket >> 3;                // dst>>10 == (dst>>7)>>3
    const int n = tail[bin * 16];
    const int2* pb = part + (size_t)bin * BIN_CAP;
    const int node0 = bucket * BNODES;
    for (int i = tid; i < n; i += 256) {
        int2 e = pb[i];
        unsigned ld = (unsigned)(e.y - node0);
        if (ld < BNODES) {
            int pos = atomicAdd(&lcur[ld], 1);
            if (pos < ELL_STRIDE) lell[ld * ELL_STRIDE + pos] = e.x;
        }
    }
    __syncthreads();

    for (int idx = tid; idx < BNODES * ELL_STRIDE; idx += 256) {
        int ln = idx / ELL_STRIDE, sl = idx - ln * ELL_STRIDE;
        int dg = lcur[ln];
        int pe = (dg + 7) & ~7;
        if (pe < 16) pe = 16;
        if (sl >= dg && sl < pe) lell[idx] = N_NODES;   // dummy zero row
    }
    __syncthreads();

    int4* dst4 = (int4*)(ell + (size_t)bucket * BNODES * ELL_STRIDE);
    const int4* src4 = (const int4*)lell;
    for (int i = tid; i < BNODES * ELL_STRIDE / 4; i += 256) dst4[i] = src4[i];
    for (int i = tid; i < BNODES; i += 256) deg[node0 + i] = lcur[i];

    // fused scale: hA[row] *= dinv (replaces k_scale); zero both dummy rows
    for (int i = tid; i < BNODES * 8; i += 256) {       // 8 uint4 per row
        int ln = i >> 3;
        int node = node0 + ln;
        if (node < N_NODES) {
            float dd = rsqrtf((float)(lcur[ln] + 1));
            uint4* p = (uint4*)(hA + (size_t)node * DIM) + (i & 7);
            uint4 v = *p;
            {   // scale2 inline
                float lo, hi;
                lo = __uint_as_float(v.x << 16) * dd; hi = __uint_as_float(v.x & 0xFFFF0000u) * dd;
                v.x = (unsigned)f2bf(lo) | ((unsigned)f2bf(hi) << 16);
                lo = __uint_as_float(v.y << 16) * dd; hi = __uint_as_float(v.y & 0xFFFF0000u) * dd;
                v.y = (unsigned)f2bf(lo) | ((unsigned)f2bf(hi) << 16);
                lo = __uint_as_float(v.z << 16) * dd; hi = __uint_as_float(v.z & 0xFFFF0000u) * dd;
                v.z = (unsigned)f2bf(lo) | ((unsigned)f2bf(hi) << 16);
                lo = __uint_as_float(v.w << 16) * dd; hi = __uint_as_float(v.w & 0xFFFF0000u) * dd;
                v.w = (unsigned)f2bf(lo) | ((unsigned)f2bf(hi) << 16);
            }
            *p = v;
        }
    }
    if (bucket == 0) {
        if (tid < 8)  ((uint4*)(hA + (size_t)N_NODES * DIM))[tid] = make_uint4(0, 0, 0, 0);
        else if (tid < 16) ((uint4*)(hB + (size_t)N_NODES * DIM))[tid - 8] = make_uint4(0, 0, 0, 0);
    }
}

// ---------------- fused gather+GEMM: agg -> +b -> relu -> @W -> *dinv -------
// 64 nodes/block, 4 waves x 16 nodes. Wave stages its 16 agg rows in LDS
// (reads only its own rows -> no barrier), then wreg-column dot, bf16 out.
// hout MUST differ from h (blocks read each other's h rows) -> ping-pong.

__global__ void __launch_bounds__(256, 4)
k_gatherW(const unsigned short* __restrict__ h,
          const int* __restrict__ deg,
          const int* __restrict__ ell,
          const float* __restrict__ bvec,
          const float* __restrict__ W,
          unsigned short* __restrict__ hout) {
    __shared__ float sh[64 * 64];               // 16 KB agg rows
    const int tid = threadIdx.x;
    const int lane = tid & 63;
    const int wv = tid >> 6;
    const int base = blockIdx.x * 64;
    const float bl = bvec[lane];

#pragma unroll 2
    for (int m = 0; m < 16; ++m) {
        int node = base + wv * 16 + m;
        if (node >= N_NODES) node = 0;          // tail block; store guarded below
        int dg = __builtin_amdgcn_readfirstlane(deg[node]);
        const int* row = ell + (size_t)node * ELL_STRIDE;

        int4 e0 = ((const int4*)row)[0];
        int4 e1 = ((const int4*)row)[1];
        int4 e2 = ((const int4*)row)[2];
        int4 e3 = ((const int4*)row)[3];
        float own = bf2f(h[(size_t)node * DIM + lane]);

        float v0  = bf2f(h[(size_t)e0.x * DIM + lane]);
        float v1  = bf2f(h[(size_t)e0.y * DIM + lane]);
        float v2  = bf2f(h[(size_t)e0.z * DIM + lane]);
        float v3  = bf2f(h[(size_t)e0.w * DIM + lane]);
        float v4  = bf2f(h[(size_t)e1.x * DIM + lane]);
        float v5  = bf2f(h[(size_t)e1.y * DIM + lane]);
        float v6  = bf2f(h[(size_t)e1.z * DIM + lane]);
        float v7  = bf2f(h[(size_t)e1.w * DIM + lane]);
        float v8  = bf2f(h[(size_t)e2.x * DIM + lane]);
        float v9  = bf2f(h[(size_t)e2.y * DIM + lane]);
        float v10 = bf2f(h[(size_t)e2.z * DIM + lane]);
        float v11 = bf2f(h[(size_t)e2.w * DIM + lane]);
        float v12 = bf2f(h[(size_t)e3.x * DIM + lane]);
        float v13 = bf2f(h[(size_t)e3.y * DIM + lane]);
        float v14 = bf2f(h[(size_t)e3.z * DIM + lane]);
        float v15 = bf2f(h[(size_t)e3.w * DIM + lane]);

        float acc = ((own + v0) + (v1 + v2)) + ((v3 + v4) + (v5 + v6))
                  + ((v7 + v8) + (v9 + v10)) + ((v11 + v12) + ((v13 + v14) + v15));

        if (dg > 16) {                          // rare, wave-uniform
            int pe = (dg + 7) & ~7;
            for (int k = 16; k < pe; k += 8) {
                int4 a = *(const int4*)(row + k);
                int4 c = *(const int4*)(row + k + 4);
                float w0 = bf2f(h[(size_t)a.x * DIM + lane]);
                float w1 = bf2f(h[(size_t)a.y * DIM + lane]);
                float w2 = bf2f(h[(size_t)a.z * DIM + lane]);
                float w3 = bf2f(h[(size_t)a.w * DIM + lane]);
                float w4 = bf2f(h[(size_t)c.x * DIM + lane]);
                float w5 = bf2f(h[(size_t)c.y * DIM + lane]);
                float w6 = bf2f(h[(size_t)c.z * DIM + lane]);
                float w7 = bf2f(h[(size_t)c.w * DIM + lane]);
                acc += ((w0 + w1) + (w2 + w3)) + ((w4 + w5) + (w6 + w7));
            }
        }

        float dd = rsqrtf((float)(dg + 1));
        float o = fmaxf(fmaf(acc, dd, bl), 0.f);    // bias + relu (layers 1,2)
        sh[(wv * 16 + m) * 64 + lane] = o;          // banks = lane%32: 2-way, free
    }

    // phase 2: row @ W, scaled by dinv[row] (wreg loaded late -> low peak VGPR)
    float wreg[64];
#pragma unroll
    for (int k = 0; k < 64; ++k) wreg[k] = W[k * DIM + lane];

#pragma unroll 4
    for (int m = 0; m < 16; ++m) {
        const float4* xr = (const float4*)&sh[(wv * 16 + m) * 64];
        float a0 = 0.f, a1 = 0.f, a2 = 0.f, a3 = 0.f;
#pragma unroll
        for (int k4 = 0; k4 < 16; ++k4) {
            float4 xv = xr[k4];                 // uniform broadcast read
            a0 = fmaf(xv.x, wreg[k4 * 4 + 0], a0);
            a1 = fmaf(xv.y, wreg[k4 * 4 + 1], a1);
            a2 = fmaf(xv.z, wreg[k4 * 4 + 2], a2);
            a3 = fmaf(xv.w, wreg[k4 * 4 + 3], a3);
        }
        int rown = base + wv * 16 + m;
        if (rown < N_NODES) {
            float res = (a0 + a1) + (a2 + a3);
            res *= rsqrtf((float)(deg[rown] + 1));
            hout[(size_t)rown * DIM + lane] = f2bf(res);
        }
    }
}

// ---------------- final gather: out = dinv*(sum) + b (fp32) -----------------

__global__ void k_gather(const unsigned short* __restrict__ h,
                         const int* __restrict__ deg,
                         const int* __restrict__ ell, const float* __restrict__ b,
                         float* __restrict__ out) {
    int node = blockIdx.x * 4 + (threadIdx.x >> 6);     // 25000*4 = 100000 exact
    const int lane = threadIdx.x & 63;
    int dg = __builtin_amdgcn_readfirstlane(deg[node]);
    const int* row = ell + (size_t)node * ELL_STRIDE;

    int4 e0 = ((const int4*)row)[0];
    int4 e1 = ((const int4*)row)[1];
    int4 e2 = ((const int4*)row)[2];
    int4 e3 = ((const int4*)row)[3];
    float own = bf2f(h[(size_t)node * DIM + lane]);

    float v0  = bf2f(h[(size_t)e0.x * DIM + lane]);
    float v1  = bf2f(h[(size_t)e0.y * DIM + lane]);
    float v2  = bf2f(h[(size_t)e0.z * DIM + lane]);
    float v3  = bf2f(h[(size_t)e0.w * DIM + lane]);
    float v4  = bf2f(h[(size_t)e1.x * DIM + lane]);
    float v5  = bf2f(h[(size_t)e1.y * DIM + lane]);
    float v6  = bf2f(h[(size_t)e1.z * DIM + lane]);
    float v7  = bf2f(h[(size_t)e1.w * DIM + lane]);
    float v8  = bf2f(h[(size_t)e2.x * DIM + lane]);
    float v9  = bf2f(h[(size_t)e2.y * DIM + lane]);
    float v10 = bf2f(h[(size_t)e2.z * DIM + lane]);
    float v11 = bf2f(h[(size_t)e2.w * DIM + lane]);
    float v12 = bf2f(h[(size_t)e3.x * DIM + lane]);
    float v13 = bf2f(h[(size_t)e3.y * DIM + lane]);
    float v14 = bf2f(h[(size_t)e3.z * DIM + lane]);
    float v15 = bf2f(h[(size_t)e3.w * DIM + lane]);

    float acc = ((own + v0) + (v1 + v2)) + ((v3 + v4) + (v5 + v6))
              + ((v7 + v8) + (v9 + v10)) + ((v11 + v12) + ((v13 + v14) + v15));

    if (dg > 16) {
        int pe = (dg + 7) & ~7;
        for (int k = 16; k < pe; k += 8) {
            int4 a = *(const int4*)(row + k);
            int4 c = *(const int4*)(row + k + 4);
            float w0 = bf2f(h[(size_t)a.x * DIM + lane]);
            float w1 = bf2f(h[(size_t)a.y * DIM + lane]);
            float w2 = bf2f(h[(size_t)a.z * DIM + lane]);
            float w3 = bf2f(h[(size_t)a.w * DIM + lane]);
            float w4 = bf2f(h[(size_t)c.x * DIM + lane]);
            float w5 = bf2f(h[(size_t)c.y * DIM + lane]);
            float w6 = bf2f(h[(size_t)c.z * DIM + lane]);
            float w7 = bf2f(h[(size_t)c.w * DIM + lane]);
            acc += ((w0 + w1) + (w2 + w3)) + ((w4 + w5) + (w6 + w7));
        }
    }

    float dd = rsqrtf((float)(dg + 1));
    out[(size_t)node * DIM + lane] = fmaf(acc, dd, b[lane]);
}

// ---------------- launch ----------------

extern "C" void kernel_launch(void* const* d_in, const int* in_sizes, int n_in,
                              void* d_out, int out_size, void* d_ws, size_t ws_size,
                              hipStream_t stream) {
    const float* x   = (const float*)d_in[0];
    const int*   ei  = (const int*)d_in[1];     // [2, E] row-major
    const float* W1  = (const float*)d_in[2];
    const float* b1  = (const float*)d_in[3];
    const float* W2  = (const float*)d_in[4];
    const float* b2  = (const float*)d_in[5];
    const float* W3  = (const float*)d_in[6];
    const float* b3  = (const float*)d_in[7];
    float* out = (float*)d_out;

    // ws layout; part overlays hbufB (part dead after k_bucket, hbufB first
    // written by gatherW layer-1)
    char* ws = (char*)d_ws;
    int*            deg   = (int*)ws;                           // 400 KB
    int*            tailp = (int*)(ws + 0x70000);               // 98 x 64B
    int*            ell   = (int*)(ws + 0xD00000);              // 19.2 MB
    unsigned short* hbufA = (unsigned short*)(ws + 0x2000000);  // 12.8 MB (+dummy)
    unsigned short* hbufB = (unsigned short*)(ws + 0x2D00000);  // 12.85 MB
    int2*           part  = (int2*)(ws + 0x2D00000);            // overlay (NBIN*BIN_CAP*8)

    k_init<<<1, 128, 0, stream>>>(tailp);

    // gemm1 (x @ W1 -> hbufA, unscaled)  ||  LDS-binned edge partition
    k_pre<<<GEMM_BLOCKS + BIN_BLOCKS, 256, 0, stream>>>(ei, x, W1, tailp, part, hbufA);
    // bucket ELL build + deg + fused hbufA scale + dummy-row zeroing
    k_bucket<<<NBUCKET, 256, 0, stream>>>(part, tailp, ell, deg, hbufA, hbufB);

    // Layer 1->2: gather(h1') + b1 + relu -> @W2 *dinv -> hbufB
    k_gatherW<<<GEMM_BLOCKS, 256, 0, stream>>>(hbufA, deg, ell, b1, W2, hbufB);
    // Layer 2->3: -> @W3 *dinv -> hbufA
    k_gatherW<<<GEMM_BLOCKS, 256, 0, stream>>>(hbufB, deg, ell, b2, W3, hbufA);
    // Layer 3 final: fp32 out
    k_gather<<<N_NODES / 4, 256, 0, stream>>>(hbufA, deg, ell, b3, out);
}